// Round 4
// baseline (510.720 us; speedup 1.0000x reference)
//
#include <hip/hip_runtime.h>
#include <hip/hip_bf16.h>
#include <stdint.h>

typedef short short8 __attribute__((ext_vector_type(8)));
typedef float f32x4 __attribute__((ext_vector_type(4)));
typedef float fvec4 __attribute__((ext_vector_type(4)));
typedef unsigned short us4 __attribute__((ext_vector_type(4)));

static __device__ __forceinline__ unsigned short f2bf(float f) {
  union { float f; uint32_t u; } v; v.f = f;
  uint32_t u = v.u;
  return (unsigned short)((u + 0x7FFFu + ((u >> 16) & 1u)) >> 16);
}

static __device__ __forceinline__ float bf2f(unsigned short u) {
  union { uint32_t u; float f; } v; v.u = (uint32_t)u << 16;
  return v.f;
}

static __device__ __forceinline__ float elu_f(float v) {
  return v > 0.0f ? v : expm1f(v);
}

// packed bf16 atomic add (fallback path only)
static __device__ __forceinline__ void atomic_pk_bf16(unsigned short* p, float lo, float hi) {
  uint32_t data = ((uint32_t)f2bf(hi) << 16) | (uint32_t)f2bf(lo);
  asm volatile("global_atomic_pk_add_bf16 %0, %1, off sc1"
               :: "v"((uint64_t)(uintptr_t)p), "v"(data) : "memory");
}

// Pack W[K][Nc] (f32, row-major) into MFMA B-fragment order (bf16)
__global__ void pack_kernel(const float* __restrict__ W, unsigned short* __restrict__ dst,
                            int KT, int Nc, int total) {
  int p = blockIdx.x * blockDim.x + threadIdx.x;
  if (p >= total) return;
  int i = p & 7;
  int l = (p >> 3) & 63;
  int rest = p >> 9;
  int kt = rest % KT;
  int nt = rest / KT;
  int krow = kt * 32 + (l >> 4) * 8 + i;
  int col = nt * 16 + (l & 15);
  dst[p] = f2bf(W[(size_t)krow * Nc + col]);
}

__global__ void hist_kernel(const int* __restrict__ col_idx, int* __restrict__ cnt, int E) {
  int i = blockIdx.x * blockDim.x + threadIdx.x;
  if (i < E) atomicAdd(&cnt[col_idx[i]], 1);
}

// single-block exclusive scan: startA[0..N] (startA[N]=E), offs = copy
__global__ __launch_bounds__(1024) void scan_kernel(const int* __restrict__ cnt,
                                                    int* __restrict__ startA,
                                                    int* __restrict__ offs, int N) {
  __shared__ int buf[1024];
  __shared__ int carry;
  const int t = threadIdx.x;
  if (t == 0) carry = 0;
  __syncthreads();
  for (int base = 0; base < N; base += 1024) {
    int v = (base + t < N) ? cnt[base + t] : 0;
    buf[t] = v;
    __syncthreads();
    for (int o = 1; o < 1024; o <<= 1) {
      int a = (t >= o) ? buf[t - o] : 0;
      __syncthreads();
      buf[t] += a;
      __syncthreads();
    }
    int c = carry;
    int excl = c + buf[t] - v;
    if (base + t < N) { startA[base + t] = excl; offs[base + t] = excl; }
    int tot = buf[1023];
    __syncthreads();
    if (t == 0) carry = c + tot;
    __syncthreads();
  }
  if (t == 0) startA[N] = carry;
}

__global__ void rank_kernel(const int* __restrict__ col_idx, int* __restrict__ offs,
                            int* __restrict__ rank, int E) {
  int i = blockIdx.x * blockDim.x + threadIdx.x;
  if (i < E) rank[i] = atomicAdd(&offs[col_idx[i]], 1);
}

#define LDA 264  // 256 + 8 pad (bf16 elems)

// 64 edges per block, 4 waves; wave w owns output cols [64w, 64w+64).
// mode 0: write h rows to hsort[rank[e]]. mode 1: atomic scatter into agg.
__global__ __launch_bounds__(256, 3) void edge_mlp_kernel(
    const float* __restrict__ x, const int* __restrict__ row_idx,
    const int* __restrict__ col_idx, const float* __restrict__ eattr,
    const float* __restrict__ b1a,
    const unsigned short* __restrict__ w1aP, const unsigned short* __restrict__ w1bP,
    const int* __restrict__ rank, unsigned short* __restrict__ hsort,
    unsigned short* __restrict__ agg, int mode) {
  __shared__ unsigned short As[64 * LDA];
  __shared__ int rowi[64];
  __shared__ int aux[64];  // rank (mode 0) or dst (mode 1)
  const int t = threadIdx.x;
  const int e0 = blockIdx.x * 64;

  if (t < 64) {
    rowi[t] = row_idx[e0 + t];
    aux[t] = (mode == 0) ? rank[e0 + t] : col_idx[e0 + t];
  }

  const int w = t >> 6, l = t & 63;
  const int lr = l & 15, lk = l >> 4;
  const unsigned short* B1 = w1aP + (size_t)(w * 32) * 512 + (size_t)l * 8;
  const unsigned short* B2 = w1bP + (size_t)(w * 32) * 512 + (size_t)l * 8;

  short8 bA[4], bB[4];
#pragma unroll
  for (int n = 0; n < 4; ++n) bA[n] = *(const short8*)(B1 + n * 4096);

  __syncthreads();

  // stage A: [64 edges][256 feats] as bf16 (x[row] | edge_attr)
  for (int idx = t; idx < 64 * 64; idx += 256) {
    int e = idx >> 6, c4 = idx & 63;
    fvec4 v;
    if (c4 < 32)
      v = *(const fvec4*)(x + (size_t)rowi[e] * 128 + c4 * 4);
    else
      v = __builtin_nontemporal_load((const fvec4*)(eattr + (size_t)(e0 + e) * 128 + (c4 - 32) * 4));
    us4 o;
    o.x = f2bf(v.x); o.y = f2bf(v.y); o.z = f2bf(v.z); o.w = f2bf(v.w);
    *(us4*)(&As[e * LDA + c4 * 4]) = o;
  }
  __syncthreads();

  f32x4 acc[4][4];
  const f32x4 zero4 = {0.f, 0.f, 0.f, 0.f};
#pragma unroll
  for (int mt = 0; mt < 4; ++mt)
#pragma unroll
    for (int nt = 0; nt < 4; ++nt) acc[mt][nt] = zero4;

  // GEMM1: [64,256] x W1a[256,256], B double-buffered
#pragma unroll
  for (int kt = 0; kt < 8; ++kt) {
    short8* bc = (kt & 1) ? bB : bA;
    short8* bn = (kt & 1) ? bA : bB;
    if (kt < 7) {
#pragma unroll
      for (int n = 0; n < 4; ++n) bn[n] = *(const short8*)(B1 + n * 4096 + (kt + 1) * 512);
    }
    short8 a[4];
#pragma unroll
    for (int mt = 0; mt < 4; ++mt)
      a[mt] = *(const short8*)(&As[(mt * 16 + lr) * LDA + kt * 32 + lk * 8]);
#pragma unroll
    for (int mt = 0; mt < 4; ++mt)
#pragma unroll
      for (int nt = 0; nt < 4; ++nt)
        acc[mt][nt] = __builtin_amdgcn_mfma_f32_16x16x32_bf16(a[mt], bc[nt], acc[mt][nt], 0, 0, 0);
  }

#pragma unroll
  for (int n = 0; n < 4; ++n) bA[n] = *(const short8*)(B2 + n * 4096);

  __syncthreads();

  // epilogue1: bias + ELU -> bf16 H
#pragma unroll
  for (int nt = 0; nt < 4; ++nt) {
    int col = w * 64 + nt * 16 + lr;
    float bias = b1a[col];
#pragma unroll
    for (int mt = 0; mt < 4; ++mt)
#pragma unroll
      for (int j = 0; j < 4; ++j) {
        float v = elu_f(acc[mt][nt][j] + bias);
        As[(mt * 16 + lk * 4 + j) * LDA + col] = f2bf(v);
      }
  }
  __syncthreads();

  // GEMM2: H[64,256] x W1b[256,256], B double-buffered
#pragma unroll
  for (int mt = 0; mt < 4; ++mt)
#pragma unroll
    for (int nt = 0; nt < 4; ++nt) acc[mt][nt] = zero4;
#pragma unroll
  for (int kt = 0; kt < 8; ++kt) {
    short8* bc = (kt & 1) ? bB : bA;
    short8* bn = (kt & 1) ? bA : bB;
    if (kt < 7) {
#pragma unroll
      for (int n = 0; n < 4; ++n) bn[n] = *(const short8*)(B2 + n * 4096 + (kt + 1) * 512);
    }
    short8 a[4];
#pragma unroll
    for (int mt = 0; mt < 4; ++mt)
      a[mt] = *(const short8*)(&As[(mt * 16 + lr) * LDA + kt * 32 + lk * 8]);
#pragma unroll
    for (int mt = 0; mt < 4; ++mt)
#pragma unroll
      for (int nt = 0; nt < 4; ++nt)
        acc[mt][nt] = __builtin_amdgcn_mfma_f32_16x16x32_bf16(a[mt], bc[nt], acc[mt][nt], 0, 0, 0);
  }

  // epilogue2 — b1b deferred to node kernel (mean(h+b) == mean(h)+b)
  if (mode == 0) {
    __syncthreads();
#pragma unroll
    for (int nt = 0; nt < 4; ++nt) {
      int col = w * 64 + nt * 16 + lr;
#pragma unroll
      for (int mt = 0; mt < 4; ++mt)
#pragma unroll
        for (int j = 0; j < 4; ++j)
          As[(mt * 16 + lk * 4 + j) * LDA + col] = f2bf(acc[mt][nt][j]);
    }
    __syncthreads();
    for (int i = t; i < 64 * 64; i += 256) {
      int row = i >> 6, c4 = i & 63;
      us4 v = *(const us4*)(&As[row * LDA + c4 * 4]);
      *(us4*)(hsort + (size_t)aux[row] * 256 + c4 * 4) = v;
    }
  } else {
    const int odd = lr & 1;
    const int colbase = w * 64 + (lr & ~1);
#pragma unroll
    for (int nt = 0; nt < 4; ++nt) {
#pragma unroll
      for (int mt = 0; mt < 4; ++mt) {
        float q0 = __shfl_xor(acc[mt][nt][0], 1);
        float q1 = __shfl_xor(acc[mt][nt][1], 1);
        float q2 = __shfl_xor(acc[mt][nt][2], 1);
        float q3 = __shfl_xor(acc[mt][nt][3], 1);
        int rbase = mt * 16 + lk * 4 + (odd ? 2 : 0);
        float lo1 = odd ? q2 : acc[mt][nt][0];
        float hi1 = odd ? acc[mt][nt][2] : q0;
        float lo2 = odd ? q3 : acc[mt][nt][1];
        float hi2 = odd ? acc[mt][nt][3] : q1;
        int n1 = aux[rbase];
        int n2 = aux[rbase + 1];
        int cc = colbase + nt * 16;
        atomic_pk_bf16(agg + ((size_t)n1 << 8) + cc, lo1, hi1);
        atomic_pk_bf16(agg + ((size_t)n2 << 8) + cc, lo2, hi2);
      }
    }
  }
}

#define LDN 392  // 384 + 8 pad

__global__ __launch_bounds__(256, 3) void node_mlp_kernel(
    const float* __restrict__ x, const unsigned short* __restrict__ hsort,
    const int* __restrict__ startA, const int* __restrict__ cnt,
    const unsigned short* __restrict__ agg, const float* __restrict__ b1b,
    const float* __restrict__ b2a, const float* __restrict__ b2b,
    const unsigned short* __restrict__ w2aP, const unsigned short* __restrict__ w2bP,
    float* __restrict__ out, int N, int mode) {
  __shared__ unsigned short As[64 * LDN];
  const int t = threadIdx.x;
  const int n0 = blockIdx.x * 64;

  const int w = t >> 6, l = t & 63;
  const int lr = l & 15, lk = l >> 4;
  const unsigned short* B1 = w2aP + (size_t)(w * 48) * 512 + (size_t)l * 8;
  const unsigned short* B2 = w2bP + (size_t)(w * 16) * 512 + (size_t)l * 8;

  short8 bA[4], bB[4];
#pragma unroll
  for (int n = 0; n < 4; ++n) bA[n] = *(const short8*)(B1 + n * 6144);

  // stage x part: cols [0,128)
  for (int idx = t; idx < 64 * 32; idx += 256) {
    int nn = idx >> 5, c4 = idx & 31;
    int node = n0 + nn;
    fvec4 v = {0.f, 0.f, 0.f, 0.f};
    if (node < N) v = *(const fvec4*)(x + (size_t)node * 128 + c4 * 4);
    us4 o;
    o.x = f2bf(v.x); o.y = f2bf(v.y); o.z = f2bf(v.z); o.w = f2bf(v.w);
    *(us4*)(&As[nn * LDN + c4 * 4]) = o;
  }

  // stage agg part: cols [128,384)
  if (mode == 0) {
    for (int k = 0; k < 16; ++k) {
      int nn = w * 16 + k;
      int node = n0 + nn;
      f32x4 sum = {0.f, 0.f, 0.f, 0.f};
      float gate = 0.f, inv = 0.f;
      if (node < N) {
        int s = startA[node], e = startA[node + 1];
        for (int r = s; r < e; ++r) {
          us4 h = *(const us4*)(hsort + (size_t)r * 256 + 4 * l);
          sum[0] += bf2f(h.x); sum[1] += bf2f(h.y);
          sum[2] += bf2f(h.z); sum[3] += bf2f(h.w);
        }
        int cn = e - s;
        if (cn > 0) { gate = 1.f; inv = 1.0f / (float)cn; }
      }
      us4 o;
      o.x = f2bf(sum[0] * inv + gate * b1b[4 * l + 0]);
      o.y = f2bf(sum[1] * inv + gate * b1b[4 * l + 1]);
      o.z = f2bf(sum[2] * inv + gate * b1b[4 * l + 2]);
      o.w = f2bf(sum[3] * inv + gate * b1b[4 * l + 3]);
      *(us4*)(&As[nn * LDN + 128 + 4 * l]) = o;
    }
  } else {
    for (int idx = t; idx < 64 * 64; idx += 256) {
      int nn = idx >> 6, c4 = idx & 63;
      int node = n0 + nn;
      fvec4 v = {0.f, 0.f, 0.f, 0.f};
      if (node < N) {
        int c = c4 * 4;
        float cn = (float)cnt[node];
        float inv = cn > 0.f ? 1.0f / cn : 0.f;
        float g = cn > 0.f ? 1.f : 0.f;
        us4 s = *(const us4*)(agg + ((size_t)node << 8) + c);
        v.x = bf2f(s.x) * inv + g * b1b[c + 0];
        v.y = bf2f(s.y) * inv + g * b1b[c + 1];
        v.z = bf2f(s.z) * inv + g * b1b[c + 2];
        v.w = bf2f(s.w) * inv + g * b1b[c + 3];
      }
      us4 o;
      o.x = f2bf(v.x); o.y = f2bf(v.y); o.z = f2bf(v.z); o.w = f2bf(v.w);
      *(us4*)(&As[nn * LDN + 128 + c4 * 4]) = o;
    }
  }
  __syncthreads();

  const f32x4 zero4 = {0.f, 0.f, 0.f, 0.f};
  f32x4 acc[4][4];
#pragma unroll
  for (int mt = 0; mt < 4; ++mt)
#pragma unroll
    for (int nt = 0; nt < 4; ++nt) acc[mt][nt] = zero4;

#pragma unroll
  for (int kt = 0; kt < 12; ++kt) {
    short8* bc = (kt & 1) ? bB : bA;
    short8* bn = (kt & 1) ? bA : bB;
    if (kt < 11) {
#pragma unroll
      for (int n = 0; n < 4; ++n) bn[n] = *(const short8*)(B1 + n * 6144 + (kt + 1) * 512);
    }
    short8 a[4];
#pragma unroll
    for (int mt = 0; mt < 4; ++mt)
      a[mt] = *(const short8*)(&As[(mt * 16 + lr) * LDN + kt * 32 + lk * 8]);
#pragma unroll
    for (int mt = 0; mt < 4; ++mt)
#pragma unroll
      for (int nt = 0; nt < 4; ++nt)
        acc[mt][nt] = __builtin_amdgcn_mfma_f32_16x16x32_bf16(a[mt], bc[nt], acc[mt][nt], 0, 0, 0);
  }

#pragma unroll
  for (int n = 0; n < 2; ++n) bA[n] = *(const short8*)(B2 + n * 4096);

  __syncthreads();

#pragma unroll
  for (int nt = 0; nt < 4; ++nt) {
    int col = w * 64 + nt * 16 + lr;
    float bias = b2a[col];
#pragma unroll
    for (int mt = 0; mt < 4; ++mt)
#pragma unroll
      for (int j = 0; j < 4; ++j) {
        float v = elu_f(acc[mt][nt][j] + bias);
        As[(mt * 16 + lk * 4 + j) * 264 + col] = f2bf(v);
      }
  }
  __syncthreads();

  f32x4 acc2[4][2];
#pragma unroll
  for (int mt = 0; mt < 4; ++mt)
#pragma unroll
    for (int nt = 0; nt < 2; ++nt) acc2[mt][nt] = zero4;
#pragma unroll
  for (int kt = 0; kt < 8; ++kt) {
    short8* bc = (kt & 1) ? bB : bA;
    short8* bn = (kt & 1) ? bA : bB;
    if (kt < 7) {
#pragma unroll
      for (int n = 0; n < 2; ++n) bn[n] = *(const short8*)(B2 + n * 4096 + (kt + 1) * 512);
    }
    short8 a[4];
#pragma unroll
    for (int mt = 0; mt < 4; ++mt)
      a[mt] = *(const short8*)(&As[(mt * 16 + lr) * 264 + kt * 32 + lk * 8]);
#pragma unroll
    for (int mt = 0; mt < 4; ++mt)
#pragma unroll
      for (int nt = 0; nt < 2; ++nt)
        acc2[mt][nt] = __builtin_amdgcn_mfma_f32_16x16x32_bf16(a[mt], bc[nt], acc2[mt][nt], 0, 0, 0);
  }

#pragma unroll
  for (int nt = 0; nt < 2; ++nt) {
    int col = w * 32 + nt * 16 + lr;
    float bias = b2b[col];
#pragma unroll
    for (int mt = 0; mt < 4; ++mt)
#pragma unroll
      for (int j = 0; j < 4; ++j) {
        int node = n0 + mt * 16 + lk * 4 + j;
        if (node < N) out[(size_t)node * 128 + col] = acc2[mt][nt][j] + bias;
      }
  }
}

extern "C" void kernel_launch(void* const* d_in, const int* in_sizes, int n_in,
                              void* d_out, int out_size, void* d_ws, size_t ws_size,
                              hipStream_t stream) {
  const float* x = (const float*)d_in[0];
  const int* ei = (const int*)d_in[1];
  const float* eattr = (const float*)d_in[2];
  const float* W1a = (const float*)d_in[5];
  const float* b1a = (const float*)d_in[6];
  const float* W1b = (const float*)d_in[7];
  const float* b1b = (const float*)d_in[8];
  const float* W2a = (const float*)d_in[9];
  const float* b2a = (const float*)d_in[10];
  const float* W2b = (const float*)d_in[11];
  const float* b2b = (const float*)d_in[12];

  const int N = in_sizes[0] / 128;   // 25000
  const int E = in_sizes[2] / 128;   // 400000
  const size_t wbytes = (size_t)(256 * 256 + 256 * 256 + 384 * 256 + 256 * 128) * 2;

  char* ws = (char*)d_ws;
  const size_t hsortB = (size_t)E * 256 * 2;
  const size_t metaB = (size_t)N * 4 + (size_t)(N + 1) * 4 + (size_t)N * 4 + (size_t)E * 4;
  const size_t needed = hsortB + metaB + 512 + wbytes;

  if (ws_size >= needed) {
    // ---------------- sorted CSR path (no value atomics) ----------------
    unsigned short* hsort = (unsigned short*)ws;
    size_t off = hsortB;
    int* cntbuf = (int*)(ws + off); off += (size_t)N * 4;
    int* startA = (int*)(ws + off); off += (size_t)(N + 1) * 4;
    int* offs   = (int*)(ws + off); off += (size_t)N * 4;
    int* rankA  = (int*)(ws + off); off += (size_t)E * 4;
    off = (off + 255) & ~(size_t)255;
    unsigned short* w1aP = (unsigned short*)(ws + off); off += 256 * 256 * 2;
    unsigned short* w1bP = (unsigned short*)(ws + off); off += 256 * 256 * 2;
    unsigned short* w2aP = (unsigned short*)(ws + off); off += 384 * 256 * 2;
    unsigned short* w2bP = (unsigned short*)(ws + off);

    (void)hipMemsetAsync(cntbuf, 0, (size_t)N * 4, stream);

    pack_kernel<<<256, 256, 0, stream>>>(W1a, w1aP, 8, 256, 256 * 256);
    pack_kernel<<<256, 256, 0, stream>>>(W1b, w1bP, 8, 256, 256 * 256);
    pack_kernel<<<384, 256, 0, stream>>>(W2a, w2aP, 12, 256, 384 * 256);
    pack_kernel<<<128, 256, 0, stream>>>(W2b, w2bP, 8, 128, 256 * 128);

    hist_kernel<<<(E + 255) / 256, 256, 0, stream>>>(ei + E, cntbuf, E);
    scan_kernel<<<1, 1024, 0, stream>>>(cntbuf, startA, offs, N);
    rank_kernel<<<(E + 255) / 256, 256, 0, stream>>>(ei + E, offs, rankA, E);

    edge_mlp_kernel<<<E / 64, 256, 0, stream>>>(x, ei, ei + E, eattr, b1a, w1aP, w1bP,
                                                rankA, hsort, hsort, 0);

    node_mlp_kernel<<<(N + 63) / 64, 256, 0, stream>>>(x, hsort, startA, cntbuf, hsort,
                                                       b1b, b2a, b2b, w2aP, w2bP,
                                                       (float*)d_out, N, 0);
  } else {
    // ---------------- fallback: round-3 atomic path ----------------
    unsigned short* agg = (unsigned short*)ws;
    int* cntbuf = (int*)(ws + (size_t)N * 256 * 2);
    size_t off = (size_t)N * 256 * 2 + (size_t)N * 4;
    off = (off + 255) & ~(size_t)255;
    unsigned short* w1aP = (unsigned short*)(ws + off); off += 256 * 256 * 2;
    unsigned short* w1bP = (unsigned short*)(ws + off); off += 256 * 256 * 2;
    unsigned short* w2aP = (unsigned short*)(ws + off); off += 384 * 256 * 2;
    unsigned short* w2bP = (unsigned short*)(ws + off);

    (void)hipMemsetAsync(ws, 0, (size_t)N * 256 * 2 + (size_t)N * 4, stream);

    pack_kernel<<<256, 256, 0, stream>>>(W1a, w1aP, 8, 256, 256 * 256);
    pack_kernel<<<256, 256, 0, stream>>>(W1b, w1bP, 8, 256, 256 * 256);
    pack_kernel<<<384, 256, 0, stream>>>(W2a, w2aP, 12, 256, 384 * 256);
    pack_kernel<<<128, 256, 0, stream>>>(W2b, w2bP, 8, 128, 256 * 128);

    hist_kernel<<<(E + 255) / 256, 256, 0, stream>>>(ei + E, cntbuf, E);

    edge_mlp_kernel<<<E / 64, 256, 0, stream>>>(x, ei, ei + E, eattr, b1a, w1aP, w1bP,
                                                nullptr, nullptr, agg, 1);

    node_mlp_kernel<<<(N + 63) / 64, 256, 0, stream>>>(x, nullptr, nullptr, cntbuf, agg,
                                                       b1b, b2a, b2b, w2aP, w2bP,
                                                       (float*)d_out, N, 1);
  }
}

// Round 5
// 377.470 us; speedup vs baseline: 1.3530x; 1.3530x over previous
//
#include <hip/hip_runtime.h>
#include <hip/hip_bf16.h>
#include <stdint.h>

typedef short short8 __attribute__((ext_vector_type(8)));
typedef float f32x4 __attribute__((ext_vector_type(4)));
typedef float fvec4 __attribute__((ext_vector_type(4)));
typedef unsigned short us4 __attribute__((ext_vector_type(4)));
typedef unsigned short us8 __attribute__((ext_vector_type(8)));

static __device__ __forceinline__ unsigned short f2bf(float f) {
  union { float f; uint32_t u; } v; v.f = f;
  uint32_t u = v.u;
  return (unsigned short)((u + 0x7FFFu + ((u >> 16) & 1u)) >> 16);
}

static __device__ __forceinline__ float bf2f(unsigned short u) {
  union { uint32_t u; float f; } v; v.u = (uint32_t)u << 16;
  return v.f;
}

// fast ELU: __expf -> v_exp_f32 (vs expm1f libm path). |err| ~1e-7, fine vs 2e-2 threshold.
static __device__ __forceinline__ float elu_f(float v) {
  return v > 0.0f ? v : __expf(v) - 1.0f;
}

// Pack W[K][Nc] (f32, row-major) into MFMA B-fragment order (bf16)
__global__ void pack_kernel(const float* __restrict__ W, unsigned short* __restrict__ dst,
                            int KT, int Nc, int total) {
  int p = blockIdx.x * blockDim.x + threadIdx.x;
  if (p >= total) return;
  int i = p & 7;
  int l = (p >> 3) & 63;
  int rest = p >> 9;
  int kt = rest % KT;
  int nt = rest / KT;
  int krow = kt * 32 + (l >> 4) * 8 + i;
  int col = nt * 16 + (l & 15);
  dst[p] = f2bf(W[(size_t)krow * Nc + col]);
}

__global__ void hist_kernel(const int* __restrict__ col_idx, int* __restrict__ cnt, int E) {
  int i = blockIdx.x * blockDim.x + threadIdx.x;
  if (i < E) atomicAdd(&cnt[col_idx[i]], 1);
}

// hierarchical scan, pass 1: per-block exclusive scan + block totals
__global__ __launch_bounds__(1024) void scan1_kernel(const int* __restrict__ cnt,
                                                     int* __restrict__ startA,
                                                     int* __restrict__ bsum, int N) {
  __shared__ int buf[1024];
  const int t = threadIdx.x;
  const int i = blockIdx.x * 1024 + t;
  int v = (i < N) ? cnt[i] : 0;
  buf[t] = v;
  __syncthreads();
  for (int o = 1; o < 1024; o <<= 1) {
    int a = (t >= o) ? buf[t - o] : 0;
    __syncthreads();
    buf[t] += a;
    __syncthreads();
  }
  if (i < N) startA[i] = buf[t] - v;  // exclusive within block
  if (t == 1023) bsum[blockIdx.x] = buf[t];
}

// pass 2: tiny serial scan of block totals (nb ~ 25)
__global__ void scan2_kernel(const int* __restrict__ bsum, int* __restrict__ boff, int nb) {
  if (threadIdx.x == 0 && blockIdx.x == 0) {
    int acc = 0;
    for (int b = 0; b < nb; ++b) { boff[b] = acc; acc += bsum[b]; }
  }
}

// pass 3: add block offsets; duplicate into offs; startA[N]=E
__global__ void scan3_kernel(int* __restrict__ startA, int* __restrict__ offs,
                             const int* __restrict__ boff, int N, int E) {
  int i = blockIdx.x * blockDim.x + threadIdx.x;
  if (i < N) {
    int s = startA[i] + boff[i >> 10];
    startA[i] = s;
    offs[i] = s;
  }
  if (i == 0) startA[N] = E;
}

__global__ void rank_kernel(const int* __restrict__ col_idx, int* __restrict__ offs,
                            int* __restrict__ rank, int E) {
  int i = blockIdx.x * blockDim.x + threadIdx.x;
  if (i < E) rank[i] = atomicAdd(&offs[col_idx[i]], 1);
}

#define LDA 264  // 256 + 8 pad (bf16 elems); 528B row = 16B-aligned

// 64 edges per block, 4 waves; wave w owns output cols [64w, 64w+64).
__global__ __launch_bounds__(256, 4) void edge_mlp_kernel(
    const float* __restrict__ x, const int* __restrict__ row_idx,
    const float* __restrict__ eattr, const float* __restrict__ b1a,
    const unsigned short* __restrict__ w1aP, const unsigned short* __restrict__ w1bP,
    const int* __restrict__ rank, unsigned short* __restrict__ hsort) {
  __shared__ __align__(16) unsigned short As[64 * LDA];
  __shared__ int rowi[64];
  __shared__ int aux[64];
  const int t = threadIdx.x;
  const int e0 = blockIdx.x * 64;

  if (t < 64) {
    rowi[t] = row_idx[e0 + t];
    aux[t] = rank[e0 + t];
  }

  const int w = t >> 6, l = t & 63;
  const int lr = l & 15, lk = l >> 4;
  const unsigned short* B1 = w1aP + (size_t)(w * 32) * 512 + (size_t)l * 8;
  const unsigned short* B2 = w1bP + (size_t)(w * 32) * 512 + (size_t)l * 8;

  short8 bA[4], bB[4];
#pragma unroll
  for (int n = 0; n < 4; ++n) bA[n] = *(const short8*)(B1 + n * 4096);

  __syncthreads();

  // stage A: [64 edges][256 feats] as bf16 (x[row] | edge_attr)
  for (int idx = t; idx < 64 * 64; idx += 256) {
    int e = idx >> 6, c4 = idx & 63;
    fvec4 v;
    if (c4 < 32)
      v = *(const fvec4*)(x + (size_t)rowi[e] * 128 + c4 * 4);
    else
      v = __builtin_nontemporal_load((const fvec4*)(eattr + (size_t)(e0 + e) * 128 + (c4 - 32) * 4));
    us4 o;
    o.x = f2bf(v.x); o.y = f2bf(v.y); o.z = f2bf(v.z); o.w = f2bf(v.w);
    *(us4*)(&As[e * LDA + c4 * 4]) = o;
  }
  __syncthreads();

  f32x4 acc[4][4];
  const f32x4 zero4 = {0.f, 0.f, 0.f, 0.f};
#pragma unroll
  for (int mt = 0; mt < 4; ++mt)
#pragma unroll
    for (int nt = 0; nt < 4; ++nt) acc[mt][nt] = zero4;

  // GEMM1: [64,256] x W1a[256,256], B double-buffered from L2
#pragma unroll
  for (int kt = 0; kt < 8; ++kt) {
    short8* bc = (kt & 1) ? bB : bA;
    short8* bn = (kt & 1) ? bA : bB;
    if (kt < 7) {
#pragma unroll
      for (int n = 0; n < 4; ++n) bn[n] = *(const short8*)(B1 + n * 4096 + (kt + 1) * 512);
    }
    short8 a[4];
#pragma unroll
    for (int mt = 0; mt < 4; ++mt)
      a[mt] = *(const short8*)(&As[(mt * 16 + lr) * LDA + kt * 32 + lk * 8]);
#pragma unroll
    for (int mt = 0; mt < 4; ++mt)
#pragma unroll
      for (int nt = 0; nt < 4; ++nt)
        acc[mt][nt] = __builtin_amdgcn_mfma_f32_16x16x32_bf16(a[mt], bc[nt], acc[mt][nt], 0, 0, 0);
  }

#pragma unroll
  for (int n = 0; n < 4; ++n) bA[n] = *(const short8*)(B2 + n * 4096);

  __syncthreads();

  // epilogue1: bias + ELU -> bf16 H (reuse As)
#pragma unroll
  for (int nt = 0; nt < 4; ++nt) {
    int col = w * 64 + nt * 16 + lr;
    float bias = b1a[col];
#pragma unroll
    for (int mt = 0; mt < 4; ++mt)
#pragma unroll
      for (int j = 0; j < 4; ++j) {
        float v = elu_f(acc[mt][nt][j] + bias);
        As[(mt * 16 + lk * 4 + j) * LDA + col] = f2bf(v);
      }
  }
  __syncthreads();

  // GEMM2: H[64,256] x W1b[256,256]
#pragma unroll
  for (int mt = 0; mt < 4; ++mt)
#pragma unroll
    for (int nt = 0; nt < 4; ++nt) acc[mt][nt] = zero4;
#pragma unroll
  for (int kt = 0; kt < 8; ++kt) {
    short8* bc = (kt & 1) ? bB : bA;
    short8* bn = (kt & 1) ? bA : bB;
    if (kt < 7) {
#pragma unroll
      for (int n = 0; n < 4; ++n) bn[n] = *(const short8*)(B2 + n * 4096 + (kt + 1) * 512);
    }
    short8 a[4];
#pragma unroll
    for (int mt = 0; mt < 4; ++mt)
      a[mt] = *(const short8*)(&As[(mt * 16 + lr) * LDA + kt * 32 + lk * 8]);
#pragma unroll
    for (int mt = 0; mt < 4; ++mt)
#pragma unroll
      for (int nt = 0; nt < 4; ++nt)
        acc[mt][nt] = __builtin_amdgcn_mfma_f32_16x16x32_bf16(a[mt], bc[nt], acc[mt][nt], 0, 0, 0);
  }

  // epilogue2: h -> LDS (b1b deferred to node kernel), then coalesced 16B-row scatter
  __syncthreads();
#pragma unroll
  for (int nt = 0; nt < 4; ++nt) {
    int col = w * 64 + nt * 16 + lr;
#pragma unroll
    for (int mt = 0; mt < 4; ++mt)
#pragma unroll
      for (int j = 0; j < 4; ++j)
        As[(mt * 16 + lk * 4 + j) * LDA + col] = f2bf(acc[mt][nt][j]);
  }
  __syncthreads();
  for (int i = t; i < 64 * 32; i += 256) {
    int row = i >> 5, g = i & 31;
    us8 v = *(const us8*)(&As[row * LDA + g * 8]);
    *(us8*)(hsort + (size_t)aux[row] * 256 + g * 8) = v;
  }
}

#define LDN 392  // 384 + 8 pad

// 64 nodes/block, 4 waves. Gather CSR rows (f32 accum), then MLP2.
__global__ __launch_bounds__(256, 3) void node_mlp_kernel(
    const float* __restrict__ x, const unsigned short* __restrict__ hsort,
    const int* __restrict__ startA, const float* __restrict__ b1b,
    const float* __restrict__ b2a, const float* __restrict__ b2b,
    const unsigned short* __restrict__ w2aP, const unsigned short* __restrict__ w2bP,
    float* __restrict__ out, int N) {
  __shared__ __align__(16) unsigned short As[64 * LDN];
  const int t = threadIdx.x;
  const int n0 = blockIdx.x * 64;

  const int w = t >> 6, l = t & 63;
  const int lr = l & 15, lk = l >> 4;
  const unsigned short* B1 = w2aP + (size_t)(w * 48) * 512 + (size_t)l * 8;
  const unsigned short* B2 = w2bP + (size_t)(w * 16) * 512 + (size_t)l * 8;

  short8 bA[4], bB[4];
#pragma unroll
  for (int n = 0; n < 4; ++n) bA[n] = *(const short8*)(B1 + n * 6144);

  // stage x part: cols [0,128)
  for (int idx = t; idx < 64 * 32; idx += 256) {
    int nn = idx >> 5, c4 = idx & 31;
    int node = n0 + nn;
    fvec4 v = {0.f, 0.f, 0.f, 0.f};
    if (node < N) v = *(const fvec4*)(x + (size_t)node * 128 + c4 * 4);
    us4 o;
    o.x = f2bf(v.x); o.y = f2bf(v.y); o.z = f2bf(v.z); o.w = f2bf(v.w);
    *(us4*)(&As[nn * LDN + c4 * 4]) = o;
  }

  // gather mean: wave w handles nodes [16w,16w+16); lane covers 8 cols (16B loads),
  // two rows in flight via lane half (l>>5); merge with shfl_xor(32).
  {
    const int c = l & 31;      // col block: cols 8c..8c+7
    const int h = l >> 5;      // row parity
    float bias[8];
#pragma unroll
    for (int i = 0; i < 8; ++i) bias[i] = b1b[c * 8 + i];

    for (int k = 0; k < 16; ++k) {
      int nn = w * 16 + k;
      int node = n0 + nn;
      float sum[8] = {0.f, 0.f, 0.f, 0.f, 0.f, 0.f, 0.f, 0.f};
      int cn = 0;
      if (node < N) {
        int s = startA[node], e = startA[node + 1];
        cn = e - s;
        for (int r = s + h; r < e; r += 2) {
          us8 hv = *(const us8*)(hsort + (size_t)r * 256 + c * 8);
#pragma unroll
          for (int i = 0; i < 8; ++i) sum[i] += bf2f(hv[i]);
        }
      }
#pragma unroll
      for (int i = 0; i < 8; ++i) sum[i] += __shfl_xor(sum[i], 32);
      float inv = cn > 0 ? 1.0f / (float)cn : 0.f;
      float gate = cn > 0 ? 1.f : 0.f;
      us8 o;
#pragma unroll
      for (int i = 0; i < 8; ++i) o[i] = f2bf(sum[i] * inv + gate * bias[i]);
      if (h == 0) *(us8*)(&As[nn * LDN + 128 + c * 8]) = o;
    }
  }
  __syncthreads();

  const f32x4 zero4 = {0.f, 0.f, 0.f, 0.f};
  f32x4 acc[4][4];
#pragma unroll
  for (int mt = 0; mt < 4; ++mt)
#pragma unroll
    for (int nt = 0; nt < 4; ++nt) acc[mt][nt] = zero4;

  // GEMM1: [64,384] x W2a[384,256]
#pragma unroll
  for (int kt = 0; kt < 12; ++kt) {
    short8* bc = (kt & 1) ? bB : bA;
    short8* bn = (kt & 1) ? bA : bB;
    if (kt < 11) {
#pragma unroll
      for (int n = 0; n < 4; ++n) bn[n] = *(const short8*)(B1 + n * 6144 + (kt + 1) * 512);
    }
    short8 a[4];
#pragma unroll
    for (int mt = 0; mt < 4; ++mt)
      a[mt] = *(const short8*)(&As[(mt * 16 + lr) * LDN + kt * 32 + lk * 8]);
#pragma unroll
    for (int mt = 0; mt < 4; ++mt)
#pragma unroll
      for (int nt = 0; nt < 4; ++nt)
        acc[mt][nt] = __builtin_amdgcn_mfma_f32_16x16x32_bf16(a[mt], bc[nt], acc[mt][nt], 0, 0, 0);
  }

#pragma unroll
  for (int n = 0; n < 2; ++n) bA[n] = *(const short8*)(B2 + n * 4096);

  __syncthreads();

  // epilogue1: bias + ELU -> H (reuse As, stride 264)
#pragma unroll
  for (int nt = 0; nt < 4; ++nt) {
    int col = w * 64 + nt * 16 + lr;
    float bias = b2a[col];
#pragma unroll
    for (int mt = 0; mt < 4; ++mt)
#pragma unroll
      for (int j = 0; j < 4; ++j) {
        float v = elu_f(acc[mt][nt][j] + bias);
        As[(mt * 16 + lk * 4 + j) * 264 + col] = f2bf(v);
      }
  }
  __syncthreads();

  // GEMM2: H[64,256] x W2b[256,128]; wave w owns cols [32w, 32w+32)
  f32x4 acc2[4][2];
#pragma unroll
  for (int mt = 0; mt < 4; ++mt)
#pragma unroll
    for (int nt = 0; nt < 2; ++nt) acc2[mt][nt] = zero4;
#pragma unroll
  for (int kt = 0; kt < 8; ++kt) {
    short8* bc = (kt & 1) ? bB : bA;
    short8* bn = (kt & 1) ? bA : bB;
    if (kt < 7) {
#pragma unroll
      for (int n = 0; n < 2; ++n) bn[n] = *(const short8*)(B2 + n * 4096 + (kt + 1) * 512);
    }
    short8 a[4];
#pragma unroll
    for (int mt = 0; mt < 4; ++mt)
      a[mt] = *(const short8*)(&As[(mt * 16 + lr) * 264 + kt * 32 + lk * 8]);
#pragma unroll
    for (int mt = 0; mt < 4; ++mt)
#pragma unroll
      for (int nt = 0; nt < 2; ++nt)
        acc2[mt][nt] = __builtin_amdgcn_mfma_f32_16x16x32_bf16(a[mt], bc[nt], acc2[mt][nt], 0, 0, 0);
  }

  // epilogue2: bias + store
#pragma unroll
  for (int nt = 0; nt < 2; ++nt) {
    int col = w * 32 + nt * 16 + lr;
    float bias = b2b[col];
#pragma unroll
    for (int mt = 0; mt < 4; ++mt)
#pragma unroll
      for (int j = 0; j < 4; ++j) {
        int node = n0 + mt * 16 + lk * 4 + j;
        if (node < N) out[(size_t)node * 128 + col] = acc2[mt][nt][j] + bias;
      }
  }
}

extern "C" void kernel_launch(void* const* d_in, const int* in_sizes, int n_in,
                              void* d_out, int out_size, void* d_ws, size_t ws_size,
                              hipStream_t stream) {
  const float* x = (const float*)d_in[0];
  const int* ei = (const int*)d_in[1];
  const float* eattr = (const float*)d_in[2];
  const float* W1a = (const float*)d_in[5];
  const float* b1a = (const float*)d_in[6];
  const float* W1b = (const float*)d_in[7];
  const float* b1b = (const float*)d_in[8];
  const float* W2a = (const float*)d_in[9];
  const float* b2a = (const float*)d_in[10];
  const float* W2b = (const float*)d_in[11];
  const float* b2b = (const float*)d_in[12];

  const int N = in_sizes[0] / 128;   // 25000
  const int E = in_sizes[2] / 128;   // 400000
  const int NB = (N + 1023) / 1024;  // scan blocks (~25)

  char* ws = (char*)d_ws;
  unsigned short* hsort = (unsigned short*)ws;
  size_t off = (size_t)E * 256 * 2;
  int* cntbuf = (int*)(ws + off); off += (size_t)N * 4;
  int* startA = (int*)(ws + off); off += (size_t)(N + 1) * 4;
  int* offs   = (int*)(ws + off); off += (size_t)N * 4;
  int* rankA  = (int*)(ws + off); off += (size_t)E * 4;
  int* bsum   = (int*)(ws + off); off += 64 * 4;
  int* boff   = (int*)(ws + off); off += 64 * 4;
  off = (off + 255) & ~(size_t)255;
  unsigned short* w1aP = (unsigned short*)(ws + off); off += 256 * 256 * 2;
  unsigned short* w1bP = (unsigned short*)(ws + off); off += 256 * 256 * 2;
  unsigned short* w2aP = (unsigned short*)(ws + off); off += 384 * 256 * 2;
  unsigned short* w2bP = (unsigned short*)(ws + off);

  (void)hipMemsetAsync(cntbuf, 0, (size_t)N * 4, stream);

  pack_kernel<<<256, 256, 0, stream>>>(W1a, w1aP, 8, 256, 256 * 256);
  pack_kernel<<<256, 256, 0, stream>>>(W1b, w1bP, 8, 256, 256 * 256);
  pack_kernel<<<384, 256, 0, stream>>>(W2a, w2aP, 12, 256, 384 * 256);
  pack_kernel<<<128, 256, 0, stream>>>(W2b, w2bP, 8, 128, 256 * 128);

  hist_kernel<<<(E + 255) / 256, 256, 0, stream>>>(ei + E, cntbuf, E);
  scan1_kernel<<<NB, 1024, 0, stream>>>(cntbuf, startA, bsum, N);
  scan2_kernel<<<1, 64, 0, stream>>>(bsum, boff, NB);
  scan3_kernel<<<(N + 255) / 256, 256, 0, stream>>>(startA, offs, boff, N, E);
  rank_kernel<<<(E + 255) / 256, 256, 0, stream>>>(ei + E, offs, rankA, E);

  edge_mlp_kernel<<<E / 64, 256, 0, stream>>>(x, ei, eattr, b1a, w1aP, w1bP, rankA, hsort);

  node_mlp_kernel<<<(N + 63) / 64, 256, 0, stream>>>(x, hsort, startA, b1b, b2a, b2b,
                                                     w2aP, w2bP, (float*)d_out, N);
}